// Round 7
// baseline (1391.735 us; speedup 1.0000x reference)
//
#include <hip/hip_runtime.h>
#include <hip/hip_bf16.h>
#include <cstdint>
#include <cstddef>

#define N_NODES_C 19385
#define N_EDGES_C 1200000
#define GNN_C 256
#define HID_C 512
#define RANK_C 512
#define NCLS_C 3
#define NGENES_C 6640
#define NBLK_C 6
#define B_C 256
#define LN_EPS 1e-5f

typedef short bf8v __attribute__((ext_vector_type(8)));
typedef float f4v __attribute__((ext_vector_type(4)));

__device__ __forceinline__ float bfu2f(unsigned short u) {
  union { unsigned int i; float f; } c; c.i = ((unsigned)u) << 16; return c.f;
}
__device__ __forceinline__ float bf_lo(unsigned u) {
  union { unsigned i; float f; } c; c.i = u << 16; return c.f;
}
__device__ __forceinline__ float bf_hi(unsigned u) {
  union { unsigned i; float f; } c; c.i = u & 0xffff0000u; return c.f;
}
__device__ __forceinline__ unsigned short f2bfu(float v) {
  union { float f; unsigned u; } c; c.f = v;
  unsigned r = c.u + 0x7FFFu + ((c.u >> 16) & 1u);
  return (unsigned short)(r >> 16);
}
__device__ __forceinline__ float gelu_tanh(float v) {
  const float x3 = v * v * v;
  return 0.5f * v * (1.f + tanhf(0.7978845608028654f * (v + 0.044715f * x3)));
}

// ---------------- batched fp32 -> bf16 convert ----------------

struct CvtSeg { const float* s; unsigned short* d; long long n; };
struct CvtArgs { CvtSeg seg[6]; int nseg; };

__global__ __launch_bounds__(256) void multicvt_kernel(CvtArgs a) {
  for (int sg = 0; sg < a.nseg; ++sg) {
    const float4* s = reinterpret_cast<const float4*>(a.seg[sg].s);
    unsigned short* d = a.seg[sg].d;
    const long long n4 = a.seg[sg].n >> 2;
    for (long long i = blockIdx.x * 256 + threadIdx.x; i < n4;
         i += (long long)gridDim.x * 256) {
      float4 v = s[i];
      ushort4 o;
      o.x = f2bfu(v.x); o.y = f2bfu(v.y); o.z = f2bfu(v.z); o.w = f2bfu(v.w);
      *reinterpret_cast<ushort4*>(d + i * 4) = o;
    }
  }
}

// ---------------- CSR build ----------------

__global__ __launch_bounds__(256) void hist_kernel(const int* __restrict__ dst,
                                                   int* __restrict__ cnt, int E) {
  int i = blockIdx.x * 256 + threadIdx.x;
  if (i < E) atomicAdd(&cnt[dst[i]], 1);
}

__global__ __launch_bounds__(1024) void scan_kernel(const int* __restrict__ cnt,
                                                    int* __restrict__ off, int n) {
  __shared__ int sums[1024];
  const int t = threadIdx.x;
  const int CH = (n + 1023) >> 10;
  const int base = t * CH;
  int s = 0;
  for (int i = 0; i < CH; ++i) {
    int idx = base + i;
    if (idx < n) s += cnt[idx];
  }
  sums[t] = s;
  __syncthreads();
  for (int d = 1; d < 1024; d <<= 1) {
    int v = (t >= d) ? sums[t - d] : 0;
    __syncthreads();
    sums[t] += v;
    __syncthreads();
  }
  int run = (t == 0) ? 0 : sums[t - 1];
  for (int i = 0; i < CH; ++i) {
    int idx = base + i;
    if (idx < n) { off[idx] = run; run += cnt[idx]; }
  }
  if (t == 0) off[n] = sums[1023];
}

__global__ __launch_bounds__(256) void fill_kernel(const int* __restrict__ src,
                                                   const int* __restrict__ dst,
                                                   const float* __restrict__ ew,
                                                   const int* __restrict__ off,
                                                   int* __restrict__ cur,
                                                   int* __restrict__ bsrc,
                                                   float* __restrict__ bw, int E) {
  int i = blockIdx.x * 256 + threadIdx.x;
  if (i < E) {
    int d = dst[i];
    int p = atomicAdd(&cur[d], 1);
    int q = off[d] + p;
    bsrc[q] = src[i] * GNN_C;
    bw[q] = ew[i];
  }
}

// ---------------- edge aggregation (full graph, conv6) ----------------

__global__ __launch_bounds__(256) void agg_full_kernel(const int* __restrict__ bsrc,
                                                       const float* __restrict__ bw,
                                                       const int* __restrict__ off,
                                                       const unsigned short* __restrict__ x,
                                                       unsigned short* __restrict__ aggbf) {
  __shared__ int ss[64];
  __shared__ float sw[64];
  const int n = blockIdx.x;
  const int t = threadIdx.x;
  const int s0 = off[n], s1 = off[n + 1];
  float acc = 0.f;
  for (int pos = s0; pos < s1; pos += 64) {
    const int cnt = min(64, s1 - pos);
    __syncthreads();
    if (t < cnt) { ss[t] = bsrc[pos + t]; sw[t] = bw[pos + t]; }
    __syncthreads();
    int j = 0;
    for (; j + 3 < cnt; j += 4) {
      const float x0 = bfu2f(x[ss[j + 0] + t]);
      const float x1 = bfu2f(x[ss[j + 1] + t]);
      const float x2 = bfu2f(x[ss[j + 2] + t]);
      const float x3 = bfu2f(x[ss[j + 3] + t]);
      acc = fmaf(x0, sw[j + 0], acc);
      acc = fmaf(x1, sw[j + 1], acc);
      acc = fmaf(x2, sw[j + 2], acc);
      acc = fmaf(x3, sw[j + 3], acc);
    }
    for (; j < cnt; ++j) acc = fmaf(bfu2f(x[ss[j] + t]), sw[j], acc);
  }
  aggbf[(size_t)n * GNN_C + t] = f2bfu(acc);
}

// ---------------- MFMA bf16 GEMM 128x128 (conv6 + gene) ----------------

#define MBK 32
#define MLDW 40

__global__ __launch_bounds__(256) void mgemm_kernel(const unsigned short* __restrict__ A,
                                                    const unsigned short* __restrict__ B,
                                                    const float* __restrict__ bias,
                                                    float* __restrict__ C,
                                                    int M, int N, int K, int transB) {
  __shared__ unsigned short As[128][MLDW];
  __shared__ unsigned short Bs[128][MLDW];
  const int t = threadIdx.x;
  const int lane = t & 63;
  const int wave = t >> 6;
  const int r0 = blockIdx.x * 128;
  const int c0 = blockIdx.y * 128;
  const int wm = (wave >> 1) * 64;
  const int wn = (wave & 1) * 64;
  const int lm = lane & 15;
  const int lq = lane >> 4;

  f4v acc[4][4];
  for (int i = 0; i < 4; ++i)
    for (int j = 0; j < 4; ++j)
      for (int r = 0; r < 4; ++r) acc[i][j][r] = 0.f;

  for (int k0 = 0; k0 < K; k0 += MBK) {
    {
      const int row = t >> 1;
      const int kof = (t & 1) * 16;
      const int gr = r0 + row;
      uint4 u0 = make_uint4(0, 0, 0, 0), u1 = u0;
      if (gr < M) {
        const uint4* p = reinterpret_cast<const uint4*>(A + (size_t)gr * K + k0 + kof);
        u0 = p[0]; u1 = p[1];
      }
      *reinterpret_cast<uint4*>(&As[row][kof]) = u0;
      *reinterpret_cast<uint4*>(&As[row][kof + 8]) = u1;
    }
    if (transB) {
      const int row = t >> 1;
      const int kof = (t & 1) * 16;
      const int gn = c0 + row;
      uint4 u0 = make_uint4(0, 0, 0, 0), u1 = u0;
      if (gn < N) {
        const uint4* p = reinterpret_cast<const uint4*>(B + (size_t)gn * K + k0 + kof);
        u0 = p[0]; u1 = p[1];
      }
      *reinterpret_cast<uint4*>(&Bs[row][kof]) = u0;
      *reinterpret_cast<uint4*>(&Bs[row][kof + 8]) = u1;
    } else {
      const int n = t & 127;
      const int kb = (t >> 7) * 16;
      const int gn = c0 + n;
      union { unsigned short s[16]; uint4 q[2]; } tmp;
      if (gn < N) {
        for (int i = 0; i < 16; ++i) tmp.s[i] = B[(size_t)(k0 + kb + i) * N + gn];
      } else {
        for (int i = 0; i < 16; ++i) tmp.s[i] = 0;
      }
      *reinterpret_cast<uint4*>(&Bs[n][kb]) = tmp.q[0];
      *reinterpret_cast<uint4*>(&Bs[n][kb + 8]) = tmp.q[1];
    }
    __syncthreads();

    bf8v a[4], b[4];
#pragma unroll
    for (int i = 0; i < 4; ++i)
      a[i] = *reinterpret_cast<const bf8v*>(&As[wm + i * 16 + lm][lq * 8]);
#pragma unroll
    for (int j = 0; j < 4; ++j)
      b[j] = *reinterpret_cast<const bf8v*>(&Bs[wn + j * 16 + lm][lq * 8]);
#pragma unroll
    for (int i = 0; i < 4; ++i)
#pragma unroll
      for (int j = 0; j < 4; ++j)
        acc[i][j] = __builtin_amdgcn_mfma_f32_16x16x32_bf16(a[i], b[j], acc[i][j], 0, 0, 0);
    __syncthreads();
  }

  for (int ti = 0; ti < 4; ++ti) {
    for (int tj = 0; tj < 4; ++tj) {
      const int col = c0 + wn + tj * 16 + lm;
      if (col >= N) continue;
      const float bv = bias ? bias[col] : 0.f;
      for (int r = 0; r < 4; ++r) {
        const int row = r0 + wm + ti * 16 + lq * 4 + r;
        if (row < M) C[(size_t)row * N + col] = acc[ti][tj][r] + bv;
      }
    }
  }
}

// ---------------- trunk LN (conv6 epilogue), IN-PLACE: x1 overwrites y ----------------

__global__ __launch_bounds__(256) void postconv6_kernel(const float* __restrict__ g,
                                                        const float* __restrict__ b,
                                                        const float* __restrict__ frozen,
                                                        float* __restrict__ yx) {
  __shared__ float sb[4];
  const int n = blockIdx.x, t = threadIdx.x;
  const float v = yx[(size_t)n * GNN_C + t];
  float s = v;
  for (int o = 32; o; o >>= 1) s += __shfl_down(s, o, 64);
  if ((t & 63) == 0) sb[t >> 6] = s;
  __syncthreads();
  const float m = (sb[0] + sb[1] + sb[2] + sb[3]) * (1.f / GNN_C);
  __syncthreads();
  const float d = v - m;
  s = d * d;
  for (int o = 32; o; o >>= 1) s += __shfl_down(s, o, 64);
  if ((t & 63) == 0) sb[t >> 6] = s;
  __syncthreads();
  const float rs = rsqrtf((sb[0] + sb[1] + sb[2] + sb[3]) * (1.f / GNN_C) + LN_EPS);
  const float xn = d * rs * g[t] + b[t];
  yx[(size_t)n * GNN_C + t] = frozen[(size_t)n * GNN_C + t] + fmaxf(xn, 0.f);
}

// ---------------- fused per-row head ----------------
// one block per batch row; 256 threads; entire conv7->bilinear chain in-kernel.

__global__ __launch_bounds__(256) void head_kernel(
    const int* __restrict__ node_idx,
    const int* __restrict__ bsrc, const float* __restrict__ bw,
    const int* __restrict__ off, const float* __restrict__ x1f,
    const unsigned short* __restrict__ w7bf, const float* __restrict__ b7,
    const float* __restrict__ g7, const float* __restrict__ bl7,
    const unsigned short* __restrict__ postWbf, const float* __restrict__ postb,
    const float* __restrict__ oov,
    const float* __restrict__ ing, const float* __restrict__ inb,
    const unsigned short* __restrict__ projWbf, const float* __restrict__ projb,
    const float* __restrict__ rbg, const float* __restrict__ rbb,
    const unsigned short* __restrict__ rbW1bf, const float* __restrict__ rbb1,
    const unsigned short* __restrict__ rbW2bf, const float* __restrict__ rbb2,
    const float* __restrict__ outg, const float* __restrict__ outb,
    const unsigned short* __restrict__ bilWbf, const float* __restrict__ bilb,
    unsigned short* __restrict__ pertbf) {
  __shared__ float xbuf[512];      // LN outputs / broadcast activations
  __shared__ float hs[512];        // residual stream
  __shared__ float tbuf[2048];     // W1 output
  __shared__ float part[4][512];   // W2 k-split partials
  __shared__ float red[4];
  __shared__ int ss[64];
  __shared__ float swv[64];

  const int b = blockIdx.x;
  const int t = threadIdx.x;
  const int rawidx = node_idx[b];
  const int n = max(rawidx, 0);

#define BLK_REDUCE(val, out)                                         \
  {                                                                  \
    float s_ = (val);                                                \
    for (int o_ = 32; o_; o_ >>= 1) s_ += __shfl_down(s_, o_, 64);   \
    if ((t & 63) == 0) red[t >> 6] = s_;                             \
    __syncthreads();                                                 \
    out = red[0] + red[1] + red[2] + red[3];                         \
    __syncthreads();                                                 \
  }

  // ---- conv7 gather: agg7 dim t over edges of node n
  float acc = 0.f;
  {
    const int s0 = off[n], s1 = off[n + 1];
    for (int pos = s0; pos < s1; pos += 64) {
      const int cnt = min(64, s1 - pos);
      __syncthreads();
      if (t < cnt) { ss[t] = bsrc[pos + t]; swv[t] = bw[pos + t]; }
      __syncthreads();
      for (int j = 0; j < cnt; ++j) acc = fmaf(x1f[ss[j] + t], swv[j], acc);
    }
  }
  __syncthreads();
  xbuf[t] = acc;
  __syncthreads();

  // ---- y7 = agg7 @ W7 + b7  (K=256, col t)
  float y = b7[t];
  {
    const unsigned short* wp = w7bf + t;
#pragma unroll 8
    for (int k = 0; k < 256; ++k) { y = fmaf(xbuf[k], bfu2f(*wp), y); wp += 256; }
  }
  // LN + relu + x1 residual -> x2
  float tot, m, d, var;
  BLK_REDUCE(y, tot); m = tot * (1.f / 256.f);
  d = y - m;
  BLK_REDUCE(d * d, var);
  {
    const float rs = rsqrtf(var * (1.f / 256.f) + LN_EPS);
    const float xn = d * rs * g7[t] + bl7[t];
    const float x2 = x1f[(size_t)n * GNN_C + t] + fmaxf(xn, 0.f);
    __syncthreads();
    xbuf[t] = x2;
    __syncthreads();
  }

  // ---- nemb = x2 @ postW + postb; oov select; in_ln
  y = postb[t];
  {
    const unsigned short* wp = postWbf + t;
#pragma unroll 8
    for (int k = 0; k < 256; ++k) { y = fmaf(xbuf[k], bfu2f(*wp), y); wp += 256; }
  }
  {
    const float h0 = (rawidx >= 0) ? y : oov[t];
    BLK_REDUCE(h0, tot); m = tot * (1.f / 256.f);
    d = h0 - m;
    BLK_REDUCE(d * d, var);
    const float rs = rsqrtf(var * (1.f / 256.f) + LN_EPS);
    __syncthreads();
    xbuf[t] = d * rs * ing[t] + inb[t];
    __syncthreads();
  }

  // ---- proj: h[512] = h0l @ projW + projb  (K=256)
  {
    float p0 = projb[t], p1 = projb[t + 256];
    const unsigned short* wp = projWbf + t;
#pragma unroll 4
    for (int k = 0; k < 256; ++k) {
      const float a = xbuf[k];
      p0 = fmaf(a, bfu2f(wp[0]), p0);
      p1 = fmaf(a, bfu2f(wp[256]), p1);
      wp += 512;
    }
    hs[t] = p0; hs[t + 256] = p1;
    __syncthreads();
  }

  // ---- residual blocks
  for (int i = 0; i < NBLK_C; ++i) {
    // LN over hs[512] -> xbuf
    {
      const float v0 = hs[t], v1 = hs[t + 256];
      BLK_REDUCE(v0 + v1, tot); m = tot * (1.f / 512.f);
      const float d0 = v0 - m, d1 = v1 - m;
      BLK_REDUCE(d0 * d0 + d1 * d1, var);
      const float rs = rsqrtf(var * (1.f / 512.f) + LN_EPS);
      xbuf[t] = d0 * rs * rbg[(size_t)i * 512 + t] + rbb[(size_t)i * 512 + t];
      xbuf[t + 256] = d1 * rs * rbg[(size_t)i * 512 + t + 256] + rbb[(size_t)i * 512 + t + 256];
      __syncthreads();
    }
    // W1 + gelu: cols t*8..t*8+7, K=512
    {
      float a0, a1, a2, a3, a4, a5, a6, a7;
      const float* bp = rbb1 + (size_t)i * 2048 + t * 8;
      a0 = bp[0]; a1 = bp[1]; a2 = bp[2]; a3 = bp[3];
      a4 = bp[4]; a5 = bp[5]; a6 = bp[6]; a7 = bp[7];
      const unsigned short* wp = rbW1bf + (size_t)i * 512 * 2048 + t * 8;
#pragma unroll 4
      for (int k = 0; k < 512; ++k) {
        const float a = xbuf[k];
        const uint4 w = *reinterpret_cast<const uint4*>(wp);
        wp += 2048;
        a0 = fmaf(a, bf_lo(w.x), a0); a1 = fmaf(a, bf_hi(w.x), a1);
        a2 = fmaf(a, bf_lo(w.y), a2); a3 = fmaf(a, bf_hi(w.y), a3);
        a4 = fmaf(a, bf_lo(w.z), a4); a5 = fmaf(a, bf_hi(w.z), a5);
        a6 = fmaf(a, bf_lo(w.w), a6); a7 = fmaf(a, bf_hi(w.w), a7);
      }
      float* tp = tbuf + t * 8;
      tp[0] = gelu_tanh(a0); tp[1] = gelu_tanh(a1);
      tp[2] = gelu_tanh(a2); tp[3] = gelu_tanh(a3);
      tp[4] = gelu_tanh(a4); tp[5] = gelu_tanh(a5);
      tp[6] = gelu_tanh(a6); tp[7] = gelu_tanh(a7);
      __syncthreads();
    }
    // W2: k-split g=t>>6 over K=2048, cols (t&63)*8
    {
      const int g = t >> 6;
      const int c = (t & 63) * 8;
      float a0 = 0.f, a1 = 0.f, a2 = 0.f, a3 = 0.f, a4 = 0.f, a5 = 0.f, a6 = 0.f, a7 = 0.f;
      const unsigned short* wp = rbW2bf + (size_t)i * 2048 * 512 + (size_t)(g * 512) * 512 + c;
      const float* tp = tbuf + g * 512;
#pragma unroll 4
      for (int k = 0; k < 512; ++k) {
        const float a = tp[k];
        const uint4 w = *reinterpret_cast<const uint4*>(wp);
        wp += 512;
        a0 = fmaf(a, bf_lo(w.x), a0); a1 = fmaf(a, bf_hi(w.x), a1);
        a2 = fmaf(a, bf_lo(w.y), a2); a3 = fmaf(a, bf_hi(w.y), a3);
        a4 = fmaf(a, bf_lo(w.z), a4); a5 = fmaf(a, bf_hi(w.z), a5);
        a6 = fmaf(a, bf_lo(w.w), a6); a7 = fmaf(a, bf_hi(w.w), a7);
      }
      float* pp = &part[g][c];
      pp[0] = a0; pp[1] = a1; pp[2] = a2; pp[3] = a3;
      pp[4] = a4; pp[5] = a5; pp[6] = a6; pp[7] = a7;
      __syncthreads();
    }
    // combine partials + bias + residual
    {
      const float s0 = part[0][t] + part[1][t] + part[2][t] + part[3][t]
                     + rbb2[(size_t)i * 512 + t];
      const float s1 = part[0][t + 256] + part[1][t + 256] + part[2][t + 256] + part[3][t + 256]
                     + rbb2[(size_t)i * 512 + t + 256];
      hs[t] += s0;
      hs[t + 256] += s1;
      __syncthreads();
    }
  }

  // ---- out_ln -> xbuf
  {
    const float v0 = hs[t], v1 = hs[t + 256];
    BLK_REDUCE(v0 + v1, tot); m = tot * (1.f / 512.f);
    const float d0 = v0 - m, d1 = v1 - m;
    BLK_REDUCE(d0 * d0 + d1 * d1, var);
    const float rs = rsqrtf(var * (1.f / 512.f) + LN_EPS);
    xbuf[t] = d0 * rs * outg[t] + outb[t];
    xbuf[t + 256] = d1 * rs * outg[t + 256] + outb[t + 256];
    __syncthreads();
  }

  // ---- bilinear: pert[1536] = hl @ bilW + bilb; write bf16
  if (t < 192) {
    const int c = t * 8;
    float a0, a1, a2, a3, a4, a5, a6, a7;
    const float* bp = bilb + c;
    a0 = bp[0]; a1 = bp[1]; a2 = bp[2]; a3 = bp[3];
    a4 = bp[4]; a5 = bp[5]; a6 = bp[6]; a7 = bp[7];
    const unsigned short* wp = bilWbf + c;
#pragma unroll 4
    for (int k = 0; k < 512; ++k) {
      const float a = xbuf[k];
      const uint4 w = *reinterpret_cast<const uint4*>(wp);
      wp += 1536;
      a0 = fmaf(a, bf_lo(w.x), a0); a1 = fmaf(a, bf_hi(w.x), a1);
      a2 = fmaf(a, bf_lo(w.y), a2); a3 = fmaf(a, bf_hi(w.y), a3);
      a4 = fmaf(a, bf_lo(w.z), a4); a5 = fmaf(a, bf_hi(w.z), a5);
      a6 = fmaf(a, bf_lo(w.w), a6); a7 = fmaf(a, bf_hi(w.w), a7);
    }
    union { unsigned short s[8]; uint4 q; } o;
    o.s[0] = f2bfu(a0); o.s[1] = f2bfu(a1); o.s[2] = f2bfu(a2); o.s[3] = f2bfu(a3);
    o.s[4] = f2bfu(a4); o.s[5] = f2bfu(a5); o.s[6] = f2bfu(a6); o.s[7] = f2bfu(a7);
    *reinterpret_cast<uint4*>(pertbf + (size_t)b * 1536 + c) = o.q;
  }
#undef BLK_REDUCE
}

// ---------------- host ----------------

extern "C" void kernel_launch(void* const* d_in, const int* in_sizes, int n_in,
                              void* d_out, int out_size, void* d_ws, size_t ws_size,
                              hipStream_t stream) {
  const int* node_idx = (const int*)d_in[0];
  const int* e_src = (const int*)d_in[1];
  const int* e_dst = e_src + N_EDGES_C;
  const float* ew = (const float*)d_in[2];
  const float* frozen = (const float*)d_in[3];
  const float* W6 = (const float*)d_in[4];
  const float* b6 = (const float*)d_in[5];
  const float* g6 = (const float*)d_in[6];
  const float* bl6 = (const float*)d_in[7];
  const float* W7 = (const float*)d_in[8];
  const float* b7 = (const float*)d_in[9];
  const float* g7 = (const float*)d_in[10];
  const float* bl7 = (const float*)d_in[11];
  const float* postW = (const float*)d_in[12];
  const float* postb = (const float*)d_in[13];
  const float* oov = (const float*)d_in[14];
  const float* ing = (const float*)d_in[15];
  const float* inb = (const float*)d_in[16];
  const float* projW = (const float*)d_in[17];
  const float* projb = (const float*)d_in[18];
  const float* rbg = (const float*)d_in[19];
  const float* rbb = (const float*)d_in[20];
  const float* rbW1 = (const float*)d_in[21];
  const float* rbb1 = (const float*)d_in[22];
  const float* rbW2 = (const float*)d_in[23];
  const float* rbb2 = (const float*)d_in[24];
  const float* outg = (const float*)d_in[25];
  const float* outb = (const float*)d_in[26];
  const float* bilW = (const float*)d_in[27];
  const float* bilb = (const float*)d_in[28];
  const float* gene = (const float*)d_in[29];
  (void)in_sizes; (void)n_in; (void)out_size; (void)ws_size;

  char* ws = (char*)d_ws;
  size_t o = 0;
  auto alloc = [&](size_t bytes) -> char* {
    char* p = ws + o;
    o += (bytes + 255) & ~(size_t)255;
    return p;
  };
  // layout (~67.8 MB total; proven budget ~73 MB):
  int* cnt = (int*)alloc((size_t)N_NODES_C * 4);
  int* off = (int*)alloc((size_t)(N_NODES_C + 1) * 4);
  int* cur = (int*)alloc((size_t)N_NODES_C * 4);
  int* bsrc = (int*)alloc((size_t)N_EDGES_C * 4);
  float* bw = (float*)alloc((size_t)N_EDGES_C * 4);
  unsigned short* frozbf = (unsigned short*)alloc((size_t)N_NODES_C * GNN_C * 2);
  // aggregion: agg6bf (9.93 MB) then, after conv6 GEMM, rbW1bf (12.58 MB)
  char* aggregion = alloc((size_t)NBLK_C * HID_C * 4 * HID_C * 2);  // 12.58 MB
  unsigned short* w6bf = (unsigned short*)alloc((size_t)GNN_C * GNN_C * 2);
  unsigned short* w7bf = (unsigned short*)alloc((size_t)GNN_C * GNN_C * 2);
  unsigned short* postWbf = (unsigned short*)alloc((size_t)GNN_C * GNN_C * 2);
  unsigned short* projWbf = (unsigned short*)alloc((size_t)GNN_C * HID_C * 2);
  unsigned short* bilWbf = (unsigned short*)alloc((size_t)HID_C * NCLS_C * RANK_C * 2);
  float* yx = (float*)alloc((size_t)N_NODES_C * GNN_C * 4);  // y6 -> in-place x1f
  unsigned short* rbW2bf = (unsigned short*)alloc((size_t)NBLK_C * 4 * HID_C * HID_C * 2);
  unsigned short* pertbf = (unsigned short*)alloc((size_t)B_C * NCLS_C * RANK_C * 2);

  unsigned short* agg6bf = (unsigned short*)aggregion;  // dead after conv6 GEMM
  unsigned short* rbW1bf = (unsigned short*)aggregion;  // written by phase B (after)
  unsigned short* genebf = frozbf;                      // frozbf dead after agg_full

  // CSR build
  (void)hipMemsetAsync(cnt, 0, (size_t)N_NODES_C * 4, stream);
  (void)hipMemsetAsync(cur, 0, (size_t)N_NODES_C * 4, stream);
  const int egrid = (N_EDGES_C + 255) / 256;
  hist_kernel<<<egrid, 256, 0, stream>>>(e_dst, cnt, N_EDGES_C);
  scan_kernel<<<1, 1024, 0, stream>>>(cnt, off, N_NODES_C);
  fill_kernel<<<egrid, 256, 0, stream>>>(e_src, e_dst, ew, off, cur, bsrc, bw, N_EDGES_C);

  // phase A converts
  {
    CvtArgs a;
    a.seg[0] = {frozen, frozbf, (long long)N_NODES_C * GNN_C};
    a.seg[1] = {W6, w6bf, GNN_C * GNN_C};
    a.seg[2] = {W7, w7bf, GNN_C * GNN_C};
    a.seg[3] = {postW, postWbf, GNN_C * GNN_C};
    a.seg[4] = {projW, projWbf, GNN_C * HID_C};
    a.seg[5] = {bilW, bilWbf, HID_C * NCLS_C * RANK_C};
    a.nseg = 6;
    multicvt_kernel<<<512, 256, 0, stream>>>(a);
  }

  // conv6 trunk
  agg_full_kernel<<<N_NODES_C, 256, 0, stream>>>(bsrc, bw, off, frozbf, agg6bf);
  {
    dim3 g((N_NODES_C + 127) / 128, GNN_C / 128);
    mgemm_kernel<<<g, 256, 0, stream>>>(agg6bf, w6bf, b6, yx, N_NODES_C, GNN_C, GNN_C, 0);
  }
  postconv6_kernel<<<N_NODES_C, 256, 0, stream>>>(g6, bl6, frozen, yx);
  // yx now holds x1 (fp32); agg6bf + frozbf dead

  // phase B converts: big head weights + gene
  {
    CvtArgs a;
    a.seg[0] = {rbW1, rbW1bf, (long long)NBLK_C * HID_C * 4 * HID_C};
    a.seg[1] = {rbW2, rbW2bf, (long long)NBLK_C * 4 * HID_C * HID_C};
    a.seg[2] = {gene, genebf, (long long)NGENES_C * RANK_C};
    a.nseg = 3;
    multicvt_kernel<<<1024, 256, 0, stream>>>(a);
  }

  // fused head: conv7 gather ... bilinear -> pertbf
  head_kernel<<<B_C, 256, 0, stream>>>(
      node_idx, bsrc, bw, off, yx,
      w7bf, b7, g7, bl7,
      postWbf, postb, oov, ing, inb,
      projWbf, projb,
      rbg, rbb, rbW1bf, rbb1, rbW2bf, rbb2,
      outg, outb, bilWbf, bilb, pertbf);

  // logits = pert[768,512] @ gene^T -> d_out fp32
  {
    dim3 g((B_C * NCLS_C) / 128, (NGENES_C + 127) / 128);
    mgemm_kernel<<<g, 256, 0, stream>>>(pertbf, genebf, nullptr, (float*)d_out,
                                        B_C * NCLS_C, NGENES_C, RANK_C, 1);
  }
}

// Round 8
// 703.175 us; speedup vs baseline: 1.9792x; 1.9792x over previous
//
#include <hip/hip_runtime.h>
#include <hip/hip_bf16.h>
#include <cstdint>
#include <cstddef>

#define N_NODES_C 19385
#define N_EDGES_C 1200000
#define GNN_C 256
#define HID_C 512
#define RANK_C 512
#define NCLS_C 3
#define NGENES_C 6640
#define NBLK_C 6
#define B_C 256
#define LN_EPS 1e-5f

typedef short bf8v __attribute__((ext_vector_type(8)));
typedef float f4v __attribute__((ext_vector_type(4)));

__device__ __forceinline__ float bfu2f(unsigned short u) {
  union { unsigned int i; float f; } c; c.i = ((unsigned)u) << 16; return c.f;
}
__device__ __forceinline__ unsigned short f2bfu(float v) {
  union { float f; unsigned u; } c; c.f = v;
  unsigned r = c.u + 0x7FFFu + ((c.u >> 16) & 1u);
  return (unsigned short)(r >> 16);
}
__device__ __forceinline__ float gelu_tanh(float v) {
  const float x3 = v * v * v;
  return 0.5f * v * (1.f + tanhf(0.7978845608028654f * (v + 0.044715f * x3)));
}

// ---------------- batched fp32 -> bf16 convert ----------------

struct CvtSeg { const float* s; unsigned short* d; long long n; };
struct CvtArgs { CvtSeg seg[2]; int nseg; };

__global__ __launch_bounds__(256) void multicvt_kernel(CvtArgs a) {
  for (int sg = 0; sg < a.nseg; ++sg) {
    const float4* s = reinterpret_cast<const float4*>(a.seg[sg].s);
    unsigned short* d = a.seg[sg].d;
    const long long n4 = a.seg[sg].n >> 2;
    for (long long i = blockIdx.x * 256 + threadIdx.x; i < n4;
         i += (long long)gridDim.x * 256) {
      float4 v = s[i];
      ushort4 o;
      o.x = f2bfu(v.x); o.y = f2bfu(v.y); o.z = f2bfu(v.z); o.w = f2bfu(v.w);
      *reinterpret_cast<ushort4*>(d + i * 4) = o;
    }
  }
}

// ---------------- batched fp32 [R,C] -> bf16 transposed [C,R] ----------------

struct TSeg { const float* s; unsigned short* d; int R, C; };
struct TArgs { TSeg seg[12]; int nseg; };

__global__ __launch_bounds__(256) void multitrans_kernel(TArgs a) {
  __shared__ float tile[32][33];
  const int tx = threadIdx.x & 31;
  const int ty = threadIdx.x >> 5;  // 8 rows/pass
  for (int sg = 0; sg < a.nseg; ++sg) {
    const int R = a.seg[sg].R, C = a.seg[sg].C;
    const int tC = C >> 5;
    const int nt = (R >> 5) * tC;
    const float* src = a.seg[sg].s;
    unsigned short* dst = a.seg[sg].d;
    for (int tid = blockIdx.x; tid < nt; tid += gridDim.x) {
      const int tr = tid / tC, tc = tid - tr * tC;
      const int r0 = tr * 32, c0 = tc * 32;
      __syncthreads();
#pragma unroll
      for (int j = 0; j < 32; j += 8)
        tile[ty + j][tx] = src[(size_t)(r0 + ty + j) * C + c0 + tx];
      __syncthreads();
#pragma unroll
      for (int j = 0; j < 32; j += 8)
        dst[(size_t)(c0 + ty + j) * R + r0 + tx] = f2bfu(tile[tx][ty + j]);
    }
  }
}

// ---------------- CSR build ----------------

__global__ __launch_bounds__(256) void hist_kernel(const int* __restrict__ dst,
                                                   int* __restrict__ cnt, int E) {
  int i = blockIdx.x * 256 + threadIdx.x;
  if (i < E) atomicAdd(&cnt[dst[i]], 1);
}

__global__ __launch_bounds__(1024) void scan_kernel(const int* __restrict__ cnt,
                                                    int* __restrict__ off, int n) {
  __shared__ int sums[1024];
  const int t = threadIdx.x;
  const int CH = (n + 1023) >> 10;
  const int base = t * CH;
  int s = 0;
  for (int i = 0; i < CH; ++i) {
    int idx = base + i;
    if (idx < n) s += cnt[idx];
  }
  sums[t] = s;
  __syncthreads();
  for (int d = 1; d < 1024; d <<= 1) {
    int v = (t >= d) ? sums[t - d] : 0;
    __syncthreads();
    sums[t] += v;
    __syncthreads();
  }
  int run = (t == 0) ? 0 : sums[t - 1];
  for (int i = 0; i < CH; ++i) {
    int idx = base + i;
    if (idx < n) { off[idx] = run; run += cnt[idx]; }
  }
  if (t == 0) off[n] = sums[1023];
}

__global__ __launch_bounds__(256) void fill_kernel(const int* __restrict__ src,
                                                   const int* __restrict__ dst,
                                                   const float* __restrict__ ew,
                                                   const int* __restrict__ off,
                                                   int* __restrict__ cur,
                                                   int* __restrict__ bsrc,
                                                   float* __restrict__ bw, int E) {
  int i = blockIdx.x * 256 + threadIdx.x;
  if (i < E) {
    int d = dst[i];
    int p = atomicAdd(&cur[d], 1);
    int q = off[d] + p;
    bsrc[q] = src[i] * GNN_C;
    bw[q] = ew[i];
  }
}

// ---------------- edge aggregation ----------------

__global__ __launch_bounds__(256) void agg_full_kernel(const int* __restrict__ bsrc,
                                                       const float* __restrict__ bw,
                                                       const int* __restrict__ off,
                                                       const unsigned short* __restrict__ x,
                                                       unsigned short* __restrict__ aggbf) {
  __shared__ int ss[64];
  __shared__ float sw[64];
  const int n = blockIdx.x;
  const int t = threadIdx.x;
  const int s0 = off[n], s1 = off[n + 1];
  float acc = 0.f;
  for (int pos = s0; pos < s1; pos += 64) {
    const int cnt = min(64, s1 - pos);
    __syncthreads();
    if (t < cnt) { ss[t] = bsrc[pos + t]; sw[t] = bw[pos + t]; }
    __syncthreads();
    int j = 0;
    for (; j + 3 < cnt; j += 4) {
      const float x0 = bfu2f(x[ss[j + 0] + t]);
      const float x1 = bfu2f(x[ss[j + 1] + t]);
      const float x2 = bfu2f(x[ss[j + 2] + t]);
      const float x3 = bfu2f(x[ss[j + 3] + t]);
      acc = fmaf(x0, sw[j + 0], acc);
      acc = fmaf(x1, sw[j + 1], acc);
      acc = fmaf(x2, sw[j + 2], acc);
      acc = fmaf(x3, sw[j + 3], acc);
    }
    for (; j < cnt; ++j) acc = fmaf(bfu2f(x[ss[j] + t]), sw[j], acc);
  }
  aggbf[(size_t)n * GNN_C + t] = f2bfu(acc);
}

// restricted aggregation (conv7 input), fp32 x1 -> bf16 out
__global__ __launch_bounds__(256) void agg_sel_kernel(const int* __restrict__ node_idx,
                                                      const int* __restrict__ bsrc,
                                                      const float* __restrict__ bw,
                                                      const int* __restrict__ off,
                                                      const float* __restrict__ x,
                                                      unsigned short* __restrict__ aggbf) {
  __shared__ int ss[64];
  __shared__ float sw[64];
  const int b = blockIdx.x;
  const int t = threadIdx.x;
  const int n = max(node_idx[b], 0);
  const int s0 = off[n], s1 = off[n + 1];
  float acc = 0.f;
  for (int pos = s0; pos < s1; pos += 64) {
    const int cnt = min(64, s1 - pos);
    __syncthreads();
    if (t < cnt) { ss[t] = bsrc[pos + t]; sw[t] = bw[pos + t]; }
    __syncthreads();
    for (int j = 0; j < cnt; ++j) acc = fmaf(x[ss[j] + t], sw[j], acc);
  }
  aggbf[(size_t)b * GNN_C + t] = f2bfu(acc);
}

// ---------------- MFMA bf16 GEMM 128x128, transB only: C = A[M,K] @ Bt[N,K]^T ----------------

#define MBK 32
#define MLDW 40

__global__ __launch_bounds__(256) void mgemm_kernel(const unsigned short* __restrict__ A,
                                                    const unsigned short* __restrict__ Bt,
                                                    const float* __restrict__ bias,
                                                    float* __restrict__ C,
                                                    int M, int N, int K) {
  __shared__ unsigned short As[128][MLDW];
  __shared__ unsigned short Bs[128][MLDW];
  const int t = threadIdx.x;
  const int lane = t & 63;
  const int wave = t >> 6;
  const int r0 = blockIdx.x * 128;
  const int c0 = blockIdx.y * 128;
  const int wm = (wave >> 1) * 64;
  const int wn = (wave & 1) * 64;
  const int lm = lane & 15;
  const int lq = lane >> 4;

  f4v acc[4][4];
  for (int i = 0; i < 4; ++i)
    for (int j = 0; j < 4; ++j)
      for (int r = 0; r < 4; ++r) acc[i][j][r] = 0.f;

  const int row = t >> 1;
  const int kof = (t & 1) * 16;
  for (int k0 = 0; k0 < K; k0 += MBK) {
    {
      const int gr = r0 + row;
      uint4 u0 = make_uint4(0, 0, 0, 0), u1 = u0;
      if (gr < M) {
        const uint4* p = reinterpret_cast<const uint4*>(A + (size_t)gr * K + k0 + kof);
        u0 = p[0]; u1 = p[1];
      }
      *reinterpret_cast<uint4*>(&As[row][kof]) = u0;
      *reinterpret_cast<uint4*>(&As[row][kof + 8]) = u1;
    }
    {
      const int gn = c0 + row;
      uint4 u0 = make_uint4(0, 0, 0, 0), u1 = u0;
      if (gn < N) {
        const uint4* p = reinterpret_cast<const uint4*>(Bt + (size_t)gn * K + k0 + kof);
        u0 = p[0]; u1 = p[1];
      }
      *reinterpret_cast<uint4*>(&Bs[row][kof]) = u0;
      *reinterpret_cast<uint4*>(&Bs[row][kof + 8]) = u1;
    }
    __syncthreads();

    bf8v a[4], b[4];
#pragma unroll
    for (int i = 0; i < 4; ++i)
      a[i] = *reinterpret_cast<const bf8v*>(&As[wm + i * 16 + lm][lq * 8]);
#pragma unroll
    for (int j = 0; j < 4; ++j)
      b[j] = *reinterpret_cast<const bf8v*>(&Bs[wn + j * 16 + lm][lq * 8]);
#pragma unroll
    for (int i = 0; i < 4; ++i)
#pragma unroll
      for (int j = 0; j < 4; ++j)
        acc[i][j] = __builtin_amdgcn_mfma_f32_16x16x32_bf16(a[i], b[j], acc[i][j], 0, 0, 0);
    __syncthreads();
  }

  for (int ti = 0; ti < 4; ++ti) {
    for (int tj = 0; tj < 4; ++tj) {
      const int col = c0 + wn + tj * 16 + lm;
      if (col >= N) continue;
      const float bv = bias ? bias[col] : 0.f;
      for (int r = 0; r < 4; ++r) {
        const int row2 = r0 + wm + ti * 16 + lq * 4 + r;
        if (row2 < M) C[(size_t)row2 * N + col] = acc[ti][tj][r] + bv;
      }
    }
  }
}

// ---------------- MFMA bf16 GEMM 64x64, transB, fused epilogue (head; dims multiple of 64) ----

__global__ __launch_bounds__(256) void mgemm64_kernel(const unsigned short* __restrict__ A,
                                                      const unsigned short* __restrict__ Bt,
                                                      const float* __restrict__ bias,
                                                      float* outF, unsigned short* outB,
                                                      int M, int N, int K, int doGelu) {
  __shared__ unsigned short As[64][MLDW];
  __shared__ unsigned short Bs[64][MLDW];
  const int t = threadIdx.x;
  const int lane = t & 63;
  const int wave = t >> 6;
  const int r0 = blockIdx.x * 64;
  const int c0 = blockIdx.y * 64;
  const int wm = (wave >> 1) * 32;
  const int wn = (wave & 1) * 32;
  const int lm = lane & 15;
  const int lq = lane >> 4;

  f4v acc[2][2];
  for (int i = 0; i < 2; ++i)
    for (int j = 0; j < 2; ++j)
      for (int r = 0; r < 4; ++r) acc[i][j][r] = 0.f;

  const int row = t >> 2;
  const int kof = (t & 3) * 8;
  for (int k0 = 0; k0 < K; k0 += MBK) {
    *reinterpret_cast<uint4*>(&As[row][kof]) =
        *reinterpret_cast<const uint4*>(A + (size_t)(r0 + row) * K + k0 + kof);
    *reinterpret_cast<uint4*>(&Bs[row][kof]) =
        *reinterpret_cast<const uint4*>(Bt + (size_t)(c0 + row) * K + k0 + kof);
    __syncthreads();
    bf8v a[2], b[2];
#pragma unroll
    for (int i = 0; i < 2; ++i)
      a[i] = *reinterpret_cast<const bf8v*>(&As[wm + i * 16 + lm][lq * 8]);
#pragma unroll
    for (int j = 0; j < 2; ++j)
      b[j] = *reinterpret_cast<const bf8v*>(&Bs[wn + j * 16 + lm][lq * 8]);
#pragma unroll
    for (int i = 0; i < 2; ++i)
#pragma unroll
      for (int j = 0; j < 2; ++j)
        acc[i][j] = __builtin_amdgcn_mfma_f32_16x16x32_bf16(a[i], b[j], acc[i][j], 0, 0, 0);
    __syncthreads();
  }

  for (int ti = 0; ti < 2; ++ti) {
    for (int tj = 0; tj < 2; ++tj) {
      const int col = c0 + wn + tj * 16 + lm;
      const float bv = bias ? bias[col] : 0.f;
      for (int r = 0; r < 4; ++r) {
        const int row2 = r0 + wm + ti * 16 + lq * 4 + r;
        float v = acc[ti][tj][r] + bv;
        if (doGelu) v = gelu_tanh(v);
        if (outF) outF[(size_t)row2 * N + col] = v;
        else outB[(size_t)row2 * N + col] = f2bfu(v);
      }
    }
  }
}

// split-K variant: grid.z slices write raw fp32 partials part[z][M][N]
__global__ __launch_bounds__(256) void skmgemm64_kernel(const unsigned short* __restrict__ A,
                                                        const unsigned short* __restrict__ Bt,
                                                        float* __restrict__ part,
                                                        int M, int N, int K, int kc) {
  __shared__ unsigned short As[64][MLDW];
  __shared__ unsigned short Bs[64][MLDW];
  const int t = threadIdx.x;
  const int lane = t & 63;
  const int wave = t >> 6;
  const int r0 = blockIdx.x * 64;
  const int c0 = blockIdx.y * 64;
  const int kBeg = blockIdx.z * kc;
  const int kEnd = kBeg + kc;
  const int wm = (wave >> 1) * 32;
  const int wn = (wave & 1) * 32;
  const int lm = lane & 15;
  const int lq = lane >> 4;

  f4v acc[2][2];
  for (int i = 0; i < 2; ++i)
    for (int j = 0; j < 2; ++j)
      for (int r = 0; r < 4; ++r) acc[i][j][r] = 0.f;

  const int row = t >> 2;
  const int kof = (t & 3) * 8;
  for (int k0 = kBeg; k0 < kEnd; k0 += MBK) {
    *reinterpret_cast<uint4*>(&As[row][kof]) =
        *reinterpret_cast<const uint4*>(A + (size_t)(r0 + row) * K + k0 + kof);
    *reinterpret_cast<uint4*>(&Bs[row][kof]) =
        *reinterpret_cast<const uint4*>(Bt + (size_t)(c0 + row) * K + k0 + kof);
    __syncthreads();
    bf8v a[2], b[2];
#pragma unroll
    for (int i = 0; i < 2; ++i)
      a[i] = *reinterpret_cast<const bf8v*>(&As[wm + i * 16 + lm][lq * 8]);
#pragma unroll
    for (int j = 0; j < 2; ++j)
      b[j] = *reinterpret_cast<const bf8v*>(&Bs[wn + j * 16 + lm][lq * 8]);
#pragma unroll
    for (int i = 0; i < 2; ++i)
#pragma unroll
      for (int j = 0; j < 2; ++j)
        acc[i][j] = __builtin_amdgcn_mfma_f32_16x16x32_bf16(a[i], b[j], acc[i][j], 0, 0, 0);
    __syncthreads();
  }

  float* out = part + (size_t)blockIdx.z * M * N;
  for (int ti = 0; ti < 2; ++ti)
    for (int tj = 0; tj < 2; ++tj) {
      const int col = c0 + wn + tj * 16 + lm;
      for (int r = 0; r < 4; ++r) {
        const int row2 = r0 + wm + ti * 16 + lq * 4 + r;
        out[(size_t)row2 * N + col] = acc[ti][tj][r];
      }
    }
}

// ---------------- LN family ----------------

__global__ __launch_bounds__(256) void postconv6_kernel(const float* __restrict__ g,
                                                        const float* __restrict__ b,
                                                        const float* __restrict__ frozen,
                                                        float* __restrict__ yx) {
  __shared__ float sb[4];
  const int n = blockIdx.x, t = threadIdx.x;
  const float v = yx[(size_t)n * GNN_C + t];
  float s = v;
  for (int o = 32; o; o >>= 1) s += __shfl_down(s, o, 64);
  if ((t & 63) == 0) sb[t >> 6] = s;
  __syncthreads();
  const float m = (sb[0] + sb[1] + sb[2] + sb[3]) * (1.f / GNN_C);
  __syncthreads();
  const float d = v - m;
  s = d * d;
  for (int o = 32; o; o >>= 1) s += __shfl_down(s, o, 64);
  if ((t & 63) == 0) sb[t >> 6] = s;
  __syncthreads();
  const float rs = rsqrtf((sb[0] + sb[1] + sb[2] + sb[3]) * (1.f / GNN_C) + LN_EPS);
  const float xn = d * rs * g[t] + b[t];
  yx[(size_t)n * GNN_C + t] = frozen[(size_t)n * GNN_C + t] + fmaxf(xn, 0.f);
}

__global__ __launch_bounds__(256) void postconv7_kernel(const float* __restrict__ y,
                                                        const float* __restrict__ g,
                                                        const float* __restrict__ b,
                                                        const int* __restrict__ idx,
                                                        const float* __restrict__ x1f,
                                                        unsigned short* __restrict__ out) {
  __shared__ float sb[4];
  const int bi = blockIdx.x, t = threadIdx.x;
  const int n = max(idx[bi], 0);
  const float v = y[(size_t)bi * GNN_C + t];
  float s = v;
  for (int o = 32; o; o >>= 1) s += __shfl_down(s, o, 64);
  if ((t & 63) == 0) sb[t >> 6] = s;
  __syncthreads();
  const float m = (sb[0] + sb[1] + sb[2] + sb[3]) * (1.f / GNN_C);
  __syncthreads();
  const float d = v - m;
  s = d * d;
  for (int o = 32; o; o >>= 1) s += __shfl_down(s, o, 64);
  if ((t & 63) == 0) sb[t >> 6] = s;
  __syncthreads();
  const float rs = rsqrtf((sb[0] + sb[1] + sb[2] + sb[3]) * (1.f / GNN_C) + LN_EPS);
  const float xn = d * rs * g[t] + b[t];
  out[(size_t)bi * GNN_C + t] = f2bfu(x1f[(size_t)n * GNN_C + t] + fmaxf(xn, 0.f));
}

__global__ __launch_bounds__(256) void h0ln_kernel(const float* __restrict__ ne,
                                                   const int* __restrict__ idx,
                                                   const float* __restrict__ oov,
                                                   const float* __restrict__ g,
                                                   const float* __restrict__ b,
                                                   unsigned short* __restrict__ out) {
  __shared__ float sb[4];
  const int bi = blockIdx.x, t = threadIdx.x;
  const float v = (idx[bi] >= 0) ? ne[(size_t)bi * GNN_C + t] : oov[t];
  float s = v;
  for (int o = 32; o; o >>= 1) s += __shfl_down(s, o, 64);
  if ((t & 63) == 0) sb[t >> 6] = s;
  __syncthreads();
  const float m = (sb[0] + sb[1] + sb[2] + sb[3]) * (1.f / GNN_C);
  __syncthreads();
  const float d = v - m;
  s = d * d;
  for (int o = 32; o; o >>= 1) s += __shfl_down(s, o, 64);
  if ((t & 63) == 0) sb[t >> 6] = s;
  __syncthreads();
  const float rs = rsqrtf((sb[0] + sb[1] + sb[2] + sb[3]) * (1.f / GNN_C) + LN_EPS);
  out[(size_t)bi * GNN_C + t] = f2bfu(d * rs * g[t] + b[t]);
}

// plain LN over 512-rows of h -> bf16
__global__ __launch_bounds__(256) void lnbf_kernel(const float* __restrict__ in,
                                                   const float* __restrict__ g,
                                                   const float* __restrict__ b,
                                                   unsigned short* __restrict__ out) {
  __shared__ float sb[4];
  const int r = blockIdx.x, t = threadIdx.x;
  const float v0 = in[(size_t)r * HID_C + t];
  const float v1 = in[(size_t)r * HID_C + t + 256];
  float s = v0 + v1;
  for (int o = 32; o; o >>= 1) s += __shfl_down(s, o, 64);
  if ((t & 63) == 0) sb[t >> 6] = s;
  __syncthreads();
  const float m = (sb[0] + sb[1] + sb[2] + sb[3]) * (1.f / HID_C);
  __syncthreads();
  const float d0 = v0 - m, d1 = v1 - m;
  s = d0 * d0 + d1 * d1;
  for (int o = 32; o; o >>= 1) s += __shfl_down(s, o, 64);
  if ((t & 63) == 0) sb[t >> 6] = s;
  __syncthreads();
  const float rs = rsqrtf((sb[0] + sb[1] + sb[2] + sb[3]) * (1.f / HID_C) + LN_EPS);
  out[(size_t)r * HID_C + t] = f2bfu(d0 * rs * g[t] + b[t]);
  out[(size_t)r * HID_C + t + 256] = f2bfu(d1 * rs * g[t + 256] + b[t + 256]);
}

// combine split-K partials + bias + residual into h, then LN (next gamma/beta) -> bf16
__global__ __launch_bounds__(256) void combln_kernel(const float* __restrict__ part,
                                                     float* __restrict__ h,
                                                     const float* __restrict__ b2,
                                                     const float* __restrict__ g,
                                                     const float* __restrict__ b,
                                                     unsigned short* __restrict__ out) {
  __shared__ float sb[4];
  const int r = blockIdx.x, t = threadIdx.x;
  const int MN = B_C * HID_C;
  const size_t o0 = (size_t)r * HID_C + t;
  const size_t o1 = o0 + 256;
  float v0 = h[o0] + b2[t] + part[o0] + part[MN + o0] + part[2 * MN + o0] + part[3 * MN + o0];
  float v1 = h[o1] + b2[t + 256] + part[o1] + part[MN + o1] + part[2 * MN + o1] + part[3 * MN + o1];
  h[o0] = v0;
  h[o1] = v1;
  float s = v0 + v1;
  for (int o = 32; o; o >>= 1) s += __shfl_down(s, o, 64);
  if ((t & 63) == 0) sb[t >> 6] = s;
  __syncthreads();
  const float m = (sb[0] + sb[1] + sb[2] + sb[3]) * (1.f / HID_C);
  __syncthreads();
  const float d0 = v0 - m, d1 = v1 - m;
  s = d0 * d0 + d1 * d1;
  for (int o = 32; o; o >>= 1) s += __shfl_down(s, o, 64);
  if ((t & 63) == 0) sb[t >> 6] = s;
  __syncthreads();
  const float rs = rsqrtf((sb[0] + sb[1] + sb[2] + sb[3]) * (1.f / HID_C) + LN_EPS);
  out[o0] = f2bfu(d0 * rs * g[t] + b[t]);
  out[o1] = f2bfu(d1 * rs * g[t + 256] + b[t + 256]);
}

// ---------------- host ----------------

extern "C" void kernel_launch(void* const* d_in, const int* in_sizes, int n_in,
                              void* d_out, int out_size, void* d_ws, size_t ws_size,
                              hipStream_t stream) {
  const int* node_idx = (const int*)d_in[0];
  const int* e_src = (const int*)d_in[1];
  const int* e_dst = e_src + N_EDGES_C;
  const float* ew = (const float*)d_in[2];
  const float* frozen = (const float*)d_in[3];
  const float* W6 = (const float*)d_in[4];
  const float* b6 = (const float*)d_in[5];
  const float* g6 = (const float*)d_in[6];
  const float* bl6 = (const float*)d_in[7];
  const float* W7 = (const float*)d_in[8];
  const float* b7 = (const float*)d_in[9];
  const float* g7 = (const float*)d_in[10];
  const float* bl7 = (const float*)d_in[11];
  const float* postW = (const float*)d_in[12];
  const float* postb = (const float*)d_in[13];
  const float* oov = (const float*)d_in[14];
  const float* ing = (const float*)d_in[15];
  const float* inb = (const float*)d_in[16];
  const float* projW = (const float*)d_in[17];
  const float* projb = (const float*)d_in[18];
  const float* rbg = (const float*)d_in[19];
  const float* rbb = (const float*)d_in[20];
  const float* rbW1 = (const float*)d_in[21];
  const float* rbb1 = (const float*)d_in[22];
  const float* rbW2 = (const float*)d_in[23];
  const float* rbb2 = (const float*)d_in[24];
  const float* outg = (const float*)d_in[25];
  const float* outb = (const float*)d_in[26];
  const float* bilW = (const float*)d_in[27];
  const float* bilb = (const float*)d_in[28];
  const float* gene = (const float*)d_in[29];
  (void)in_sizes; (void)n_in; (void)out_size; (void)ws_size;

  char* ws = (char*)d_ws;
  size_t o = 0;
  auto alloc = [&](size_t bytes) -> char* {
    char* p = ws + o;
    o += (bytes + 255) & ~(size_t)255;
    return p;
  };
  int* cnt = (int*)alloc((size_t)N_NODES_C * 4);
  int* off = (int*)alloc((size_t)(N_NODES_C + 1) * 4);
  int* cur = (int*)alloc((size_t)N_NODES_C * 4);
  int* bsrc = (int*)alloc((size_t)N_EDGES_C * 4);
  float* bw = (float*)alloc((size_t)N_EDGES_C * 4);
  unsigned short* frozbf = (unsigned short*)alloc((size_t)N_NODES_C * GNN_C * 2);
  // aggregion: agg6bf (9.93 MB, dead after conv6 GEMM) then rbW1t (12.58 MB, phase B)
  char* aggregion = alloc((size_t)NBLK_C * HID_C * 4 * HID_C * 2);
  unsigned short* w6t = (unsigned short*)alloc((size_t)GNN_C * GNN_C * 2);
  unsigned short* w7t = (unsigned short*)alloc((size_t)GNN_C * GNN_C * 2);
  unsigned short* postWt = (unsigned short*)alloc((size_t)GNN_C * GNN_C * 2);
  unsigned short* projWt = (unsigned short*)alloc((size_t)HID_C * GNN_C * 2);
  unsigned short* bilWt = (unsigned short*)alloc((size_t)NCLS_C * RANK_C * HID_C * 2);
  float* yx = (float*)alloc((size_t)N_NODES_C * GNN_C * 4);  // y6 -> in-place x1
  unsigned short* rbW2t = (unsigned short*)alloc((size_t)NBLK_C * 4 * HID_C * HID_C * 2);
  float* part = (float*)alloc((size_t)4 * B_C * HID_C * 4);
  unsigned short* agg7bf = (unsigned short*)alloc((size_t)B_C * GNN_C * 2);
  float* y7b = (float*)alloc((size_t)B_C * GNN_C * 4);
  unsigned short* x2bf = (unsigned short*)alloc((size_t)B_C * GNN_C * 2);
  float* nemb = (float*)alloc((size_t)B_C * GNN_C * 4);
  unsigned short* h0lbf = (unsigned short*)alloc((size_t)B_C * GNN_C * 2);
  float* h = (float*)alloc((size_t)B_C * HID_C * 4);
  unsigned short* tbf = (unsigned short*)alloc((size_t)B_C * HID_C * 2);
  unsigned short* ubf = (unsigned short*)alloc((size_t)B_C * 4 * HID_C * 2);
  unsigned short* pertbf = (unsigned short*)alloc((size_t)B_C * NCLS_C * RANK_C * 2);

  unsigned short* agg6bf = (unsigned short*)aggregion;
  unsigned short* rbW1t = (unsigned short*)aggregion;
  unsigned short* genebf = frozbf;  // frozbf dead after agg_full

  // CSR build
  (void)hipMemsetAsync(cnt, 0, (size_t)N_NODES_C * 4, stream);
  (void)hipMemsetAsync(cur, 0, (size_t)N_NODES_C * 4, stream);
  const int egrid = (N_EDGES_C + 255) / 256;
  hist_kernel<<<egrid, 256, 0, stream>>>(e_dst, cnt, N_EDGES_C);
  scan_kernel<<<1, 1024, 0, stream>>>(cnt, off, N_NODES_C);
  fill_kernel<<<egrid, 256, 0, stream>>>(e_src, e_dst, ew, off, cur, bsrc, bw, N_EDGES_C);

  // phase A: frozen convert + small weight transposes
  {
    CvtArgs a;
    a.seg[0] = {frozen, frozbf, (long long)N_NODES_C * GNN_C};
    a.nseg = 1;
    multicvt_kernel<<<512, 256, 0, stream>>>(a);
  }
  {
    TArgs a;
    a.seg[0] = {W6, w6t, GNN_C, GNN_C};
    a.seg[1] = {W7, w7t, GNN_C, GNN_C};
    a.seg[2] = {postW, postWt, GNN_C, GNN_C};
    a.seg[3] = {projW, projWt, GNN_C, HID_C};
    a.seg[4] = {bilW, bilWt, HID_C, NCLS_C * RANK_C};
    a.nseg = 5;
    multitrans_kernel<<<512, 256, 0, stream>>>(a);
  }

  // conv6 trunk
  agg_full_kernel<<<N_NODES_C, 256, 0, stream>>>(bsrc, bw, off, frozbf, agg6bf);
  {
    dim3 g((N_NODES_C + 127) / 128, GNN_C / 128);
    mgemm_kernel<<<g, 256, 0, stream>>>(agg6bf, w6t, b6, yx, N_NODES_C, GNN_C, GNN_C);
  }
  postconv6_kernel<<<N_NODES_C, 256, 0, stream>>>(g6, bl6, frozen, yx);
  // yx = x1 fp32; agg6bf + frozbf dead

  // phase B: rb weight transposes (into aggregion + rbW2t) + gene convert
  {
    TArgs a;
    for (int i = 0; i < NBLK_C; ++i) {
      a.seg[i] = {rbW1 + (size_t)i * HID_C * 4 * HID_C,
                  rbW1t + (size_t)i * HID_C * 4 * HID_C, HID_C, 4 * HID_C};
      a.seg[6 + i] = {rbW2 + (size_t)i * 4 * HID_C * HID_C,
                      rbW2t + (size_t)i * 4 * HID_C * HID_C, 4 * HID_C, HID_C};
    }
    a.nseg = 12;
    multitrans_kernel<<<2048, 256, 0, stream>>>(a);
  }
  {
    CvtArgs a;
    a.seg[0] = {gene, genebf, (long long)NGENES_C * RANK_C};
    a.nseg = 1;
    multicvt_kernel<<<512, 256, 0, stream>>>(a);
  }

  // head: conv7
  agg_sel_kernel<<<B_C, 256, 0, stream>>>(node_idx, bsrc, bw, off, yx, agg7bf);
  {
    dim3 g(B_C / 64, GNN_C / 64);
    mgemm64_kernel<<<g, 256, 0, stream>>>(agg7bf, w7t, b7, y7b, nullptr,
                                          B_C, GNN_C, GNN_C, 0);
  }
  postconv7_kernel<<<B_C, 256, 0, stream>>>(y7b, g7, bl7, node_idx, yx, x2bf);

  // post_mp + OOV + in_ln
  {
    dim3 g(B_C / 64, GNN_C / 64);
    mgemm64_kernel<<<g, 256, 0, stream>>>(x2bf, postWt, postb, nemb, nullptr,
                                          B_C, GNN_C, GNN_C, 0);
  }
  h0ln_kernel<<<B_C, 256, 0, stream>>>(nemb, node_idx, oov, ing, inb, h0lbf);

  // proj_in -> h fp32
  {
    dim3 g(B_C / 64, HID_C / 64);
    mgemm64_kernel<<<g, 256, 0, stream>>>(h0lbf, projWt, projb, h, nullptr,
                                          B_C, HID_C, GNN_C, 0);
  }
  lnbf_kernel<<<B_C, 256, 0, stream>>>(h, rbg, rbb, tbf);

  // residual blocks: W1(gelu) -> W2 split-K -> combine+LN(next)
  for (int i = 0; i < NBLK_C; ++i) {
    {
      dim3 g(B_C / 64, (4 * HID_C) / 64);
      mgemm64_kernel<<<g, 256, 0, stream>>>(tbf, rbW1t + (size_t)i * HID_C * 4 * HID_C,
                                            rbb1 + (size_t)i * 4 * HID_C, nullptr, ubf,
                                            B_C, 4 * HID_C, HID_C, 1);
    }
    {
      dim3 g(B_C / 64, HID_C / 64, 4);
      skmgemm64_kernel<<<g, 256, 0, stream>>>(ubf, rbW2t + (size_t)i * 4 * HID_C * HID_C,
                                              part, B_C, HID_C, 4 * HID_C, HID_C);
    }
    const float* gn = (i < NBLK_C - 1) ? rbg + (size_t)(i + 1) * HID_C : outg;
    const float* bn = (i < NBLK_C - 1) ? rbb + (size_t)(i + 1) * HID_C : outb;
    combln_kernel<<<B_C, 256, 0, stream>>>(part, h, rbb2 + (size_t)i * HID_C, gn, bn, tbf);
  }

  // bilinear -> pert bf16
  {
    dim3 g(B_C / 64, (NCLS_C * RANK_C) / 64);
    mgemm64_kernel<<<g, 256, 0, stream>>>(tbf, bilWt, bilb, nullptr, pertbf,
                                          B_C, NCLS_C * RANK_C, HID_C, 0);
  }

  // logits = pert[768,512] @ gene^T -> d_out fp32
  {
    dim3 g((B_C * NCLS_C) / 128, (NGENES_C + 127) / 128);
    mgemm_kernel<<<g, 256, 0, stream>>>(pertbf, genebf, nullptr, (float*)d_out,
                                        B_C * NCLS_C, NGENES_C, RANK_C);
  }
}